// Round 2
// baseline (2319.446 us; speedup 1.0000x reference)
//
#include <hip/hip_runtime.h>
#include <hip/hip_bf16.h>

#define HID 128

typedef __attribute__((ext_vector_type(8))) short short8;
typedef __attribute__((ext_vector_type(4))) float f32x4;
typedef __attribute__((ext_vector_type(4))) unsigned int u32x4;

__device__ __forceinline__ short f2bf(float x) {
    __bf16 b = (__bf16)x;
    return __builtin_bit_cast(short, b);
}

// ---------------------------------------------------------------------------
// Prepass 1: pack W1 (256x128 fp32, k-major rows) into MFMA-B fragment order:
// bpk[((n*8 + f)*64 + lane)*8 + j] = bf16( W1[(f*32 + (lane>>4)*8 + j)*128 + n*16 + (lane&15)] )
// so the main kernel's B-fragment load is one contiguous 16B ds_read per lane.
// ---------------------------------------------------------------------------
__global__ void pack_w1_kernel(const float* __restrict__ W1, short* __restrict__ bpk) {
    int t = blockIdx.x * 256 + threadIdx.x;   // 0..4095 = n*512 + f*64 + l
    int f = (t >> 6) & 7;
    int l = t & 63;
    int n = t >> 9;
    int c = l & 15, kb = l >> 4;
    int k0 = f * 32 + kb * 8;
    short8 v;
#pragma unroll
    for (int j = 0; j < 8; ++j)
        v[j] = f2bf(W1[(k0 + j) * HID + n * 16 + c]);
    *reinterpret_cast<short8*>(&bpk[t * 8]) = v;
}

// ---------------------------------------------------------------------------
// Prepass 2: convert the node-embedding table fp32 -> bf16 (halves gather
// bytes in the main kernel and removes all in-loop v_cvt work).
// ---------------------------------------------------------------------------
__global__ __launch_bounds__(256) void conv_emb_kernel(
    const float* __restrict__ emb, short* __restrict__ bemb, int n8) {
    int i = blockIdx.x * 256 + threadIdx.x;
    if (i >= n8) return;
    f32x4 x0 = *reinterpret_cast<const f32x4*>(emb + (size_t)i * 8);
    f32x4 x1 = *reinterpret_cast<const f32x4*>(emb + (size_t)i * 8 + 4);
    short8 v;
#pragma unroll
    for (int j = 0; j < 4; ++j) {
        v[j]     = f2bf(x0[j]);
        v[4 + j] = f2bf(x1[j]);
    }
    *reinterpret_cast<short8*>(&bemb[(size_t)i * 8]) = v;
}

// ---------------------------------------------------------------------------
// Main kernel. Block = 1024 threads = 16 waves sharing one 64KB LDS copy of
// packed W1 (2 blocks/CU -> 32 waves/CU occupancy cap). Each wave owns 64
// edges: 4 M-tiles x 8 N-tiles of mfma_f32_16x16x32_bf16 over K=256, then the
// fp32 epilogue relu(h+b1)@W2+b2 with a 16-lane shuffle reduce.
// MODE: 0 = bf16 table + pre-packed W1 (full ws), 1 = fp32 gather + packed W1,
//       2 = fp32 gather + in-block W1 pack (no usable ws).
// ---------------------------------------------------------------------------
template <int MODE>
__global__ __launch_bounds__(1024, 8) void edge_head_kernel(
    const float* __restrict__ emb,
    const short* __restrict__ bemb,
    const void* __restrict__ src_raw,
    const void* __restrict__ tgt_raw,
    const float* __restrict__ W1,
    const float* __restrict__ b1,
    const float* __restrict__ W2,
    const float* __restrict__ b2,
    const short* __restrict__ bpk,
    float* __restrict__ out,
    int E)
{
    __shared__ short lds_b[32768];   // 64 KB: packed W1 (B-operand)

    const int tid = threadIdx.x;

    // int64-vs-int32 index detection (JAX may demote int64 -> int32):
    // little-endian int64 (< 2^31) has every odd dword == 0.
    int i64f = 1;
    {
        const int* s32 = (const int*)src_raw;
#pragma unroll
        for (int i = 1; i < 32; i += 2) i64f &= (s32[i] == 0);
    }

    // ---- stage packed B into LDS
    if (MODE != 2) {
        const u32x4* g = (const u32x4*)bpk;
        u32x4* d = (u32x4*)lds_b;
#pragma unroll
        for (int i = 0; i < 4; ++i) d[i * 1024 + tid] = g[i * 1024 + tid];
    } else {
        // fallback: pack W1 fp32 -> LDS in-block (coalesced reads, scattered writes)
        for (int i = 0; i < 32; ++i) {
            int idx = i * 1024 + tid;            // 0..32767 over W1
            int col = idx & 127;
            int k   = idx >> 7;
            int n = col >> 4, cc = col & 15;
            int f = k >> 5, kb = (k >> 3) & 3, j = k & 7;
            int l2 = kb * 16 + cc;
            lds_b[(((n * 8 + f) * 64 + l2) << 3) + j] = f2bf(W1[idx]);
        }
    }
    __syncthreads();

    const int l = tid & 63;
    const int wid = tid >> 6;
    const int c = l & 15;      // edge-within-M-tile / C-col within N-tile
    const int g = l >> 4;      // k-group / C-row-group
    const long long e0 = (long long)blockIdx.x * 1024 + wid * 64;

    // ---- per-M-tile gathered row pointers
    const short* bsp[4];
    const short* btp[4];
    const float* fsp[4];
    const float* ftp[4];
#pragma unroll
    for (int m = 0; m < 4; ++m) {
        long long e = e0 + m * 16 + c;
        if (e >= E) e = E - 1;
        long long si, ti;
        if (i64f) {
            si = ((const long long*)src_raw)[e];
            ti = ((const long long*)tgt_raw)[e];
        } else {
            si = ((const int*)src_raw)[e];
            ti = ((const int*)tgt_raw)[e];
        }
        if (MODE == 0) {
            bsp[m] = bemb + (size_t)si * HID;
            btp[m] = bemb + (size_t)ti * HID;
        } else {
            fsp[m] = emb + (size_t)si * HID;
            ftp[m] = emb + (size_t)ti * HID;
        }
    }

    f32x4 acc[4][8];
#pragma unroll
    for (int m = 0; m < 4; ++m)
#pragma unroll
        for (int n = 0; n < 8; ++n)
            acc[m][n] = (f32x4){0.f, 0.f, 0.f, 0.f};

    const int koff = g * 8;
#pragma unroll
    for (int f = 0; f < 8; ++f) {          // K-steps of 32 (f<4: src half, f>=4: tgt half)
        short8 afr[4];
        const int k0 = (f & 3) * 32 + koff;
#pragma unroll
        for (int m = 0; m < 4; ++m) {
            if (MODE == 0) {
                const short* p = (f < 4 ? bsp[m] : btp[m]) + k0;
                afr[m] = *reinterpret_cast<const short8*>(p);
            } else {
                const float* p = (f < 4 ? fsp[m] : ftp[m]) + k0;
                f32x4 x0 = *reinterpret_cast<const f32x4*>(p);
                f32x4 x1 = *reinterpret_cast<const f32x4*>(p + 4);
                short8 a;
#pragma unroll
                for (int j = 0; j < 4; ++j) {
                    a[j]     = f2bf(x0[j]);
                    a[4 + j] = f2bf(x1[j]);
                }
                afr[m] = a;
            }
        }
#pragma unroll
        for (int n = 0; n < 8; ++n) {
            short8 bfr = *reinterpret_cast<const short8*>(&lds_b[((n * 8 + f) * 64 + l) * 8]);
#pragma unroll
            for (int m = 0; m < 4; ++m)
                acc[m][n] = __builtin_amdgcn_mfma_f32_16x16x32_bf16(afr[m], bfr, acc[m][n], 0, 0, 0);
        }
    }

    // ---- epilogue: out[e] = relu(h + b1) @ W2 + b2, fp32
    float b1v[8], w2v[8];
#pragma unroll
    for (int n = 0; n < 8; ++n) {
        b1v[n] = b1[n * 16 + c];
        w2v[n] = W2[n * 16 + c];
    }
    const float b2s = b2[0];

#pragma unroll
    for (int m = 0; m < 4; ++m) {
        float s[4] = {0.f, 0.f, 0.f, 0.f};
#pragma unroll
        for (int n = 0; n < 8; ++n) {
#pragma unroll
            for (int r = 0; r < 4; ++r)
                s[r] += fmaxf(acc[m][n][r] + b1v[n], 0.f) * w2v[n];
        }
#pragma unroll
        for (int w = 1; w < 16; w <<= 1) {
#pragma unroll
            for (int r = 0; r < 4; ++r)
                s[r] += __shfl_xor(s[r], w, 16);
        }
        if (c == 0) {
            const long long eb = e0 + m * 16 + g * 4;
#pragma unroll
            for (int r = 0; r < 4; ++r)
                if (eb + r < E) out[eb + r] = s[r] + b2s;
        }
    }
}

extern "C" void kernel_launch(void* const* d_in, const int* in_sizes, int n_in,
                              void* d_out, int out_size, void* d_ws, size_t ws_size,
                              hipStream_t stream) {
    const float* emb = (const float*)d_in[0];
    const void*  src = d_in[1];
    const void*  tgt = d_in[2];
    // d_in[3] = edge_type_idx (selector; params passed are already the selected ones)
    const float* W1 = (const float*)d_in[4];
    const float* b1 = (const float*)d_in[5];
    const float* W2 = (const float*)d_in[6];
    const float* b2 = (const float*)d_in[7];
    float* out = (float*)d_out;

    const int E = in_sizes[1];
    const int embN = in_sizes[0];             // node_embeddings element count
    const size_t need_full = 65536 + (size_t)embN * sizeof(short);

    short* bpk  = (short*)d_ws;
    short* bemb = (short*)((char*)d_ws + 65536);

    int mode;
    if (ws_size >= need_full)       mode = 0;
    else if (ws_size >= 65536)      mode = 1;
    else                            mode = 2;

    if (mode != 2)
        pack_w1_kernel<<<16, 256, 0, stream>>>(W1, bpk);
    if (mode == 0) {
        const int n8 = embN / 8;
        conv_emb_kernel<<<(n8 + 255) / 256, 256, 0, stream>>>(emb, bemb, n8);
    }

    const int grid = (E + 1023) / 1024;
    if (mode == 0)
        edge_head_kernel<0><<<grid, 1024, 0, stream>>>(emb, bemb, src, tgt, W1, b1, W2, b2, bpk, out, E);
    else if (mode == 1)
        edge_head_kernel<1><<<grid, 1024, 0, stream>>>(emb, bemb, src, tgt, W1, b1, W2, b2, bpk, out, E);
    else
        edge_head_kernel<2><<<grid, 1024, 0, stream>>>(emb, bemb, src, tgt, W1, b1, W2, b2, bpk, out, E);
}

// Round 3
// 160.287 us; speedup vs baseline: 14.4706x; 14.4706x over previous
//
#include <hip/hip_runtime.h>
#include <hip/hip_bf16.h>

#define HID 128

typedef __attribute__((ext_vector_type(8))) short short8;
typedef __attribute__((ext_vector_type(4))) float f32x4;
typedef __attribute__((ext_vector_type(4))) unsigned int u32x4;

__device__ __forceinline__ short f2bf(float x) {
    __bf16 b = (__bf16)x;
    return __builtin_bit_cast(short, b);
}

// ---------------------------------------------------------------------------
// Prepass 1: pack W1 (256x128 fp32, k-major rows) into MFMA-B fragment order:
// bpk[((n*8 + f)*64 + lane)*8 + j] = bf16( W1[(f*32 + (lane>>4)*8 + j)*128 + n*16 + (lane&15)] )
// so the main kernel's B-fragment load is one contiguous 16B ds_read per lane.
// ---------------------------------------------------------------------------
__global__ void pack_w1_kernel(const float* __restrict__ W1, short* __restrict__ bpk) {
    int t = blockIdx.x * 256 + threadIdx.x;   // 0..4095 = n*512 + f*64 + l
    int f = (t >> 6) & 7;
    int l = t & 63;
    int n = t >> 9;
    int c = l & 15, kb = l >> 4;
    int k0 = f * 32 + kb * 8;
    short8 v;
#pragma unroll
    for (int j = 0; j < 8; ++j)
        v[j] = f2bf(W1[(k0 + j) * HID + n * 16 + c]);
    *reinterpret_cast<short8*>(&bpk[t * 8]) = v;
}

// ---------------------------------------------------------------------------
// Prepass 2: convert node-embedding table fp32 -> bf16 (halves gather bytes,
// removes all in-loop v_cvt work from the main kernel).
// ---------------------------------------------------------------------------
__global__ __launch_bounds__(256) void conv_emb_kernel(
    const float* __restrict__ emb, short* __restrict__ bemb, int n8) {
    int i = blockIdx.x * 256 + threadIdx.x;
    if (i >= n8) return;
    f32x4 x0 = *reinterpret_cast<const f32x4*>(emb + (size_t)i * 8);
    f32x4 x1 = *reinterpret_cast<const f32x4*>(emb + (size_t)i * 8 + 4);
    short8 v;
#pragma unroll
    for (int j = 0; j < 4; ++j) {
        v[j]     = f2bf(x0[j]);
        v[4 + j] = f2bf(x1[j]);
    }
    *reinterpret_cast<short8*>(&bemb[(size_t)i * 8]) = v;
}

// ---------------------------------------------------------------------------
// Main kernel. Block = 512 threads = 8 waves sharing one 64KB LDS copy of
// packed W1. Each wave owns 32 edges: 2 M-tiles x 8 N-tiles of
// mfma_f32_16x16x32_bf16 over K=256 (acc = 64 f32 -> fits 128-VGPR budget,
// 4 waves/EU, 2 blocks/CU = 16 waves/CU). fp32 epilogue relu(h+b1)@W2+b2
// with a 16-lane shuffle reduce.
// MODE: 0 = bf16 table + packed W1, 1 = fp32 gather + packed W1,
//       2 = fp32 gather + in-block W1 pack (no usable ws).
// ---------------------------------------------------------------------------
template <int MODE>
__global__ __launch_bounds__(512, 4) void edge_head_kernel(
    const float* __restrict__ emb,
    const short* __restrict__ bemb,
    const void* __restrict__ src_raw,
    const void* __restrict__ tgt_raw,
    const float* __restrict__ W1,
    const float* __restrict__ b1,
    const float* __restrict__ W2,
    const float* __restrict__ b2,
    const short* __restrict__ bpk,
    float* __restrict__ out,
    int E)
{
    __shared__ short lds_b[32768];   // 64 KB: packed W1 (B-operand)

    const int tid = threadIdx.x;

    // int64-vs-int32 index detection (JAX may demote int64 -> int32):
    // little-endian int64 (< 2^31) has every odd dword == 0.
    int i64f = 1;
    {
        const int* s32 = (const int*)src_raw;
#pragma unroll
        for (int i = 1; i < 32; i += 2) i64f &= (s32[i] == 0);
    }

    // ---- stage packed B into LDS
    if (MODE != 2) {
        const u32x4* g = (const u32x4*)bpk;
        u32x4* d = (u32x4*)lds_b;
#pragma unroll
        for (int i = 0; i < 8; ++i) d[i * 512 + tid] = g[i * 512 + tid];
    } else {
        for (int i = 0; i < 64; ++i) {
            int idx = i * 512 + tid;            // 0..32767 over W1
            int col = idx & 127;
            int k   = idx >> 7;
            int n = col >> 4, cc = col & 15;
            int f = k >> 5, kb = (k >> 3) & 3, j = k & 7;
            int l2 = kb * 16 + cc;
            lds_b[(((n * 8 + f) * 64 + l2) << 3) + j] = f2bf(W1[idx]);
        }
    }
    __syncthreads();

    const int l = tid & 63;
    const int wid = tid >> 6;
    const int c = l & 15;      // edge-within-M-tile / C-col within N-tile
    const int g = l >> 4;      // k-group / C-row-group
    const long long e0 = (long long)blockIdx.x * 256 + wid * 32;

    // ---- per-M-tile gathered row offsets (32-bit element offsets: idx*128)
    unsigned so[2], to[2];
#pragma unroll
    for (int m = 0; m < 2; ++m) {
        long long e = e0 + m * 16 + c;
        if (e >= E) e = E - 1;
        long long si, ti;
        if (i64f) {
            si = ((const long long*)src_raw)[e];
            ti = ((const long long*)tgt_raw)[e];
        } else {
            si = ((const int*)src_raw)[e];
            ti = ((const int*)tgt_raw)[e];
        }
        so[m] = (unsigned)si * HID;
        to[m] = (unsigned)ti * HID;
    }

    f32x4 acc[2][8];
#pragma unroll
    for (int m = 0; m < 2; ++m)
#pragma unroll
        for (int n = 0; n < 8; ++n)
            acc[m][n] = (f32x4){0.f, 0.f, 0.f, 0.f};

    const int koff = g * 8;
#pragma unroll
    for (int f = 0; f < 8; ++f) {          // K-steps of 32 (f<4: src half, f>=4: tgt half)
        short8 afr[2];
        const int k0 = (f & 3) * 32 + koff;
#pragma unroll
        for (int m = 0; m < 2; ++m) {
            const unsigned off = (f < 4 ? so[m] : to[m]) + k0;
            if (MODE == 0) {
                afr[m] = *reinterpret_cast<const short8*>(bemb + off);
            } else {
                f32x4 x0 = *reinterpret_cast<const f32x4*>(emb + off);
                f32x4 x1 = *reinterpret_cast<const f32x4*>(emb + off + 4);
                short8 a;
#pragma unroll
                for (int j = 0; j < 4; ++j) {
                    a[j]     = f2bf(x0[j]);
                    a[4 + j] = f2bf(x1[j]);
                }
                afr[m] = a;
            }
        }
#pragma unroll
        for (int n = 0; n < 8; ++n) {
            short8 bfr = *reinterpret_cast<const short8*>(&lds_b[((n * 8 + f) * 64 + l) * 8]);
#pragma unroll
            for (int m = 0; m < 2; ++m)
                acc[m][n] = __builtin_amdgcn_mfma_f32_16x16x32_bf16(afr[m], bfr, acc[m][n], 0, 0, 0);
        }
    }

    // ---- epilogue: out[e] = relu(h + b1) @ W2 + b2, fp32
    float b1v[8], w2v[8];
#pragma unroll
    for (int n = 0; n < 8; ++n) {
        b1v[n] = b1[n * 16 + c];
        w2v[n] = W2[n * 16 + c];
    }
    const float b2s = b2[0];

#pragma unroll
    for (int m = 0; m < 2; ++m) {
        float s[4] = {0.f, 0.f, 0.f, 0.f};
#pragma unroll
        for (int n = 0; n < 8; ++n) {
#pragma unroll
            for (int r = 0; r < 4; ++r)
                s[r] += fmaxf(acc[m][n][r] + b1v[n], 0.f) * w2v[n];
        }
#pragma unroll
        for (int w = 1; w < 16; w <<= 1) {
#pragma unroll
            for (int r = 0; r < 4; ++r)
                s[r] += __shfl_xor(s[r], w, 16);
        }
        if (c == 0) {
            const long long eb = e0 + m * 16 + g * 4;
#pragma unroll
            for (int r = 0; r < 4; ++r)
                if (eb + r < E) out[eb + r] = s[r] + b2s;
        }
    }
}

extern "C" void kernel_launch(void* const* d_in, const int* in_sizes, int n_in,
                              void* d_out, int out_size, void* d_ws, size_t ws_size,
                              hipStream_t stream) {
    const float* emb = (const float*)d_in[0];
    const void*  src = d_in[1];
    const void*  tgt = d_in[2];
    // d_in[3] = edge_type_idx (selector; params passed are already the selected ones)
    const float* W1 = (const float*)d_in[4];
    const float* b1 = (const float*)d_in[5];
    const float* W2 = (const float*)d_in[6];
    const float* b2 = (const float*)d_in[7];
    float* out = (float*)d_out;

    const int E = in_sizes[1];
    const int embN = in_sizes[0];             // node_embeddings element count
    const size_t need_full = 65536 + (size_t)embN * sizeof(short);

    short* bpk  = (short*)d_ws;
    short* bemb = (short*)((char*)d_ws + 65536);

    int mode;
    if (ws_size >= need_full)       mode = 0;
    else if (ws_size >= 65536)      mode = 1;
    else                            mode = 2;

    if (mode != 2)
        pack_w1_kernel<<<16, 256, 0, stream>>>(W1, bpk);
    if (mode == 0) {
        const int n8 = embN / 8;
        conv_emb_kernel<<<(n8 + 255) / 256, 256, 0, stream>>>(emb, bemb, n8);
    }

    const int grid = (E + 255) / 256;
    if (mode == 0)
        edge_head_kernel<0><<<grid, 512, 0, stream>>>(emb, bemb, src, tgt, W1, b1, W2, b2, bpk, out, E);
    else if (mode == 1)
        edge_head_kernel<1><<<grid, 512, 0, stream>>>(emb, bemb, src, tgt, W1, b1, W2, b2, bpk, out, E);
    else
        edge_head_kernel<2><<<grid, 512, 0, stream>>>(emb, bemb, src, tgt, W1, b1, W2, b2, bpk, out, E);
}